// Round 4
// baseline (6301.947 us; speedup 1.0000x reference)
//
#include <hip/hip_runtime.h>
#include <stdint.h>

#define N_POINTS  400000
#define WIDTH     64
#define M_SAMPLES 1000              // N_POINTS / 400
#define NBLK      64
#define NTHR      256
#define NW        (NTHR / 64)       // 4 waves per block
#define NREC      (NBLK * NW)       // 256 consensus records per round
#define NTOT      (NBLK * NTHR)     // 16384 threads
#define PPT       25                // ceil(400000 / 16384)
#define ROWU64    (4 * NREC)        // 4 planes (key,x,y,z) x 256 records
// mailbox: 2 rows x 1024 u64 = 16 KB in d_ws, double-buffered by (i & 1)

#define LOADSLOT(p) __hip_atomic_load((p), __ATOMIC_RELAXED, __HIP_MEMORY_SCOPE_AGENT)
#define STORESLOT(p, v) __hip_atomic_store((p), (v), __ATOMIC_RELAXED, __HIP_MEMORY_SCOPE_AGENT)

__device__ inline unsigned long long shfl_xor_u64(unsigned long long x, int m) {
    unsigned int lo = (unsigned int)x;
    unsigned int hi = (unsigned int)(x >> 32);
    lo = __shfl_xor(lo, m, 64);
    hi = __shfl_xor(hi, m, 64);
    return ((unsigned long long)hi << 32) | lo;
}

__global__ void fps_init(unsigned long long* slot, int* out) {
    int t = blockIdx.x * blockDim.x + threadIdx.x;
    if (t < 2 * ROWU64) slot[t] = 0ull;   // tag 0 != any live tag (i >= 1)
    if (t == 0) out[0] = 0;               // seed index
}

__global__ __launch_bounds__(NTHR)
void fps_main(const float* __restrict__ feats, int* __restrict__ out,
              unsigned long long* __restrict__ slot)
{
    const int tid  = threadIdx.x;
    const int bid  = blockIdx.x;
    const int lane = tid & 63;
    const int wid  = tid >> 6;
    const int gid  = bid * NTHR + tid;
    const int rec  = bid * NW + wid;     // this wave's record id [0,256)

    // Register-resident points + running min squared distance
    float px[PPT], py[PPT], pz[PPT], dd[PPT];
#pragma unroll
    for (int k = 0; k < PPT; k++) {
        int j = gid + k * NTOT;
        if (j < N_POINTS) {
            px[k] = feats[(size_t)j * WIDTH + 0];
            py[k] = feats[(size_t)j * WIDTH + 1];
            pz[k] = feats[(size_t)j * WIDTH + 2];
        } else {
            px[k] = 0.f; py[k] = 0.f; pz[k] = 0.f;
        }
        dd[k] = 1e10f;          // matches jnp.full(..., 1e10, f32)
    }

    // Seed pivot = point 0 (loaded once; never touch feats again)
    float qx = feats[0], qy = feats[1], qz = feats[2];

    for (int i = 1; i < M_SAMPLES; i++) {
        const unsigned tag = (unsigned)i;

        // ---- distance update + local argmax (track winning coords) ----
        unsigned long long best = 0ull;
        float bx = 0.f, by = 0.f, bz = 0.f;
#pragma unroll
        for (int k = 0; k < PPT; k++) {
            int j = gid + k * NTOT;
            // IEEE ops in reference order; _rn intrinsics block fp-contract
            float dx = __fsub_rn(px[k], qx);
            float dy = __fsub_rn(py[k], qy);
            float dz = __fsub_rn(pz[k], qz);
            float d  = __fadd_rn(__fadd_rn(__fmul_rn(dx, dx), __fmul_rn(dy, dy)),
                                 __fmul_rn(dz, dz));
            float nd = fminf(dd[k], d);
            dd[k] = nd;
            if (j < N_POINTS) {
                // key: [63:32]=dist bits, [28:10]=(N-idx) (19b), [9:0]=0 (tag room)
                // max key = max dist, ties -> lowest index (argmax semantics)
                unsigned long long key =
                    ((unsigned long long)__float_as_uint(nd) << 32) |
                    ((unsigned long long)(unsigned)(N_POINTS - j) << 10);
                if (key > best) { best = key; bx = px[k]; by = py[k]; bz = pz[k]; }
            }
        }

        // ---- wave butterfly carrying the payload (key + coords) ----
#pragma unroll
        for (int m = 32; m > 0; m >>= 1) {
            unsigned long long ok = shfl_xor_u64(best, m);
            float ox = __shfl_xor(bx, m, 64);
            float oy = __shfl_xor(by, m, 64);
            float oz = __shfl_xor(bz, m, 64);
            if (ok > best) { best = ok; bx = ox; by = oy; bz = oz; }
        }

        // ---- publish this wave's record (4 planes, tag-validated) ----
        unsigned long long* row = slot + (size_t)(i & 1) * ROWU64;
        unsigned long long* rA = row;            // keys
        unsigned long long* rB = row + NREC;     // x
        unsigned long long* rC = row + 2 * NREC; // y
        unsigned long long* rD = row + 3 * NREC; // z
        if (lane == 0) {
            unsigned long long t64 = (unsigned long long)tag;
            STORESLOT(rA + rec, best | t64);
            STORESLOT(rB + rec, ((unsigned long long)__float_as_uint(bx) << 32) | t64);
            STORESLOT(rC + rec, ((unsigned long long)__float_as_uint(by) << 32) | t64);
            STORESLOT(rD + rec, ((unsigned long long)__float_as_uint(bz) << 32) | t64);
        }

        // ---- all-wave poll: lane l owns records {l, l+64, l+128, l+192} ----
        // Plane-transposed layout: each load instruction is lane-contiguous
        // (512 B = 4 cache lines, not 64). Non-sticky re-load is safe: a valid
        // slot cannot be overwritten while any wave still polls this round.
        unsigned long long a0, a1, a2, a3, b0, b1, b2, b3;
        unsigned long long c0, c1, c2, c3, e0, e1, e2, e3;
        for (;;) {
            a0 = LOADSLOT(rA + lane);       a1 = LOADSLOT(rA + lane + 64);
            a2 = LOADSLOT(rA + lane + 128); a3 = LOADSLOT(rA + lane + 192);
            b0 = LOADSLOT(rB + lane);       b1 = LOADSLOT(rB + lane + 64);
            b2 = LOADSLOT(rB + lane + 128); b3 = LOADSLOT(rB + lane + 192);
            c0 = LOADSLOT(rC + lane);       c1 = LOADSLOT(rC + lane + 64);
            c2 = LOADSLOT(rC + lane + 128); c3 = LOADSLOT(rC + lane + 192);
            e0 = LOADSLOT(rD + lane);       e1 = LOADSLOT(rD + lane + 64);
            e2 = LOADSLOT(rD + lane + 128); e3 = LOADSLOT(rD + lane + 192);
            bool ok = ((unsigned)(a0 & 1023u) == tag) & ((unsigned)(a1 & 1023u) == tag)
                    & ((unsigned)(a2 & 1023u) == tag) & ((unsigned)(a3 & 1023u) == tag)
                    & ((unsigned)(b0 & 1023u) == tag) & ((unsigned)(b1 & 1023u) == tag)
                    & ((unsigned)(b2 & 1023u) == tag) & ((unsigned)(b3 & 1023u) == tag)
                    & ((unsigned)(c0 & 1023u) == tag) & ((unsigned)(c1 & 1023u) == tag)
                    & ((unsigned)(c2 & 1023u) == tag) & ((unsigned)(c3 & 1023u) == tag)
                    & ((unsigned)(e0 & 1023u) == tag) & ((unsigned)(e1 & 1023u) == tag)
                    & ((unsigned)(e2 & 1023u) == tag) & ((unsigned)(e3 & 1023u) == tag);
            if (ok) break;
        }

        // ---- reduce 4 local records, then wave butterfly with payload ----
        unsigned long long K = a0, Bx = b0, By = c0, Bz = e0;
        if (a1 > K) { K = a1; Bx = b1; By = c1; Bz = e1; }
        if (a2 > K) { K = a2; Bx = b2; By = c2; Bz = e2; }
        if (a3 > K) { K = a3; Bx = b3; By = c3; Bz = e3; }
        float X = __uint_as_float((unsigned)(Bx >> 32));
        float Y = __uint_as_float((unsigned)(By >> 32));
        float Z = __uint_as_float((unsigned)(Bz >> 32));
#pragma unroll
        for (int m = 32; m > 0; m >>= 1) {
            unsigned long long oK = shfl_xor_u64(K, m);
            float oX = __shfl_xor(X, m, 64);
            float oY = __shfl_xor(Y, m, 64);
            float oZ = __shfl_xor(Z, m, 64);
            if (oK > K) { K = oK; X = oX; Y = oY; Z = oZ; }
        }

        // Winner: index from key, coords from payload. No memory on the path.
        qx = X; qy = Y; qz = Z;
        if (bid == 0 && tid == 0)
            out[i] = (int)(N_POINTS - (unsigned)((K >> 10) & 0x7FFFFu));
    }
}

extern "C" void kernel_launch(void* const* d_in, const int* in_sizes, int n_in,
                              void* d_out, int out_size, void* d_ws, size_t ws_size,
                              hipStream_t stream) {
    const float* feats = (const float*)d_in[0];
    int* out = (int*)d_out;
    unsigned long long* slot = (unsigned long long*)d_ws;  // 16 KB mailbox

    fps_init<<<(2 * ROWU64 + 255) / 256, 256, 0, stream>>>(slot, out);
    // 64 blocks x 256 thr: 1 block/CU -> co-residency guaranteed
    fps_main<<<NBLK, NTHR, 0, stream>>>(feats, out, slot);
}

// Round 5
// 4174.972 us; speedup vs baseline: 1.5095x; 1.5095x over previous
//
#include <hip/hip_runtime.h>
#include <stdint.h>

#define N_POINTS  400000
#define WIDTH     64
#define M_SAMPLES 1000              // N_POINTS / 400
#define NBLK      64
#define NTHR      256
#define NW        (NTHR / 64)       // 4 waves per block
#define NTOT      (NBLK * NTHR)     // 16384 threads
#define PPT       25                // ceil(400000 / 16384)
#define ROWU64    (4 * NBLK)        // 4 planes (key,x,y,z) x 64 block-records
// mailbox: 2 rows x 256 u64 = 4 KB in d_ws, double-buffered by (i & 1)

#define LOADSLOT(p)     __hip_atomic_load((p), __ATOMIC_RELAXED, __HIP_MEMORY_SCOPE_AGENT)
#define STORESLOT(p, v) __hip_atomic_store((p), (v), __ATOMIC_RELAXED, __HIP_MEMORY_SCOPE_AGENT)

__device__ inline unsigned long long shfl_xor_u64(unsigned long long x, int m) {
    unsigned int lo = (unsigned int)x;
    unsigned int hi = (unsigned int)(x >> 32);
    lo = __shfl_xor(lo, m, 64);
    hi = __shfl_xor(hi, m, 64);
    return ((unsigned long long)hi << 32) | lo;
}

__global__ void fps_init(unsigned long long* slot, int* out) {
    int t = blockIdx.x * blockDim.x + threadIdx.x;
    if (t < 2 * ROWU64) slot[t] = 0ull;   // tag 0: first uses are tag 1 / tag 2
    if (t == 0) out[0] = 0;               // seed index
}

__global__ __launch_bounds__(NTHR)
void fps_main(const float* __restrict__ feats, int* __restrict__ out,
              unsigned long long* __restrict__ slot)
{
    const int tid  = threadIdx.x;
    const int bid  = blockIdx.x;
    const int lane = tid & 63;
    const int wid  = tid >> 6;
    const int gid  = bid * NTHR + tid;

    // Register-resident points + running min squared distance
    float px[PPT], py[PPT], pz[PPT], dd[PPT];
#pragma unroll
    for (int k = 0; k < PPT; k++) {
        int j = gid + k * NTOT;
        if (j < N_POINTS) {
            px[k] = feats[(size_t)j * WIDTH + 0];
            py[k] = feats[(size_t)j * WIDTH + 1];
            pz[k] = feats[(size_t)j * WIDTH + 2];
        } else {
            px[k] = 0.f; py[k] = 0.f; pz[k] = 0.f;
        }
        dd[k] = 1e10f;          // matches jnp.full(..., 1e10, f32)
    }

    __shared__ unsigned long long ldsk[NW];      // per-wave candidate key
    __shared__ float ldsx[NW], ldsy[NW], ldsz[NW];
    __shared__ unsigned long long s_key;
    __shared__ float s_x, s_y, s_z;

    // Seed pivot = point 0 (only feats touch after the initial load)
    float qx = feats[0], qy = feats[1], qz = feats[2];

    for (int i = 1; i < M_SAMPLES; i++) {
        const unsigned tag2 = (unsigned)(i & 3);

        // ---- distance update + per-thread argmax (f32 compare, lowest j on tie) ----
        float bnd, bx, by, bz; int bj;
        {
            float dx = __fsub_rn(px[0], qx);
            float dy = __fsub_rn(py[0], qy);
            float dz = __fsub_rn(pz[0], qz);
            float d  = __fadd_rn(__fadd_rn(__fmul_rn(dx, dx), __fmul_rn(dy, dy)),
                                 __fmul_rn(dz, dz));
            float nd = fminf(dd[0], d);
            dd[0] = nd;
            bnd = nd; bj = gid; bx = px[0]; by = py[0]; bz = pz[0];
        }
#pragma unroll
        for (int k = 1; k < PPT; k++) {
            int j = gid + k * NTOT;
            float dx = __fsub_rn(px[k], qx);
            float dy = __fsub_rn(py[k], qy);
            float dz = __fsub_rn(pz[k], qz);
            float d  = __fadd_rn(__fadd_rn(__fmul_rn(dx, dx), __fmul_rn(dy, dy)),
                                 __fmul_rn(dz, dz));
            float nd = fminf(dd[k], d);
            dd[k] = nd;
            bool valid = (k < PPT - 1) || (j < N_POINTS);  // compile-time except k=24
            if (valid && nd > bnd) { bnd = nd; bj = j; bx = px[k]; by = py[k]; bz = pz[k]; }
        }

        // key: [63:32]=dist bits (nonneg -> monotone), [22:2]=(N-j) (19b), [1:0]=tag
        // max key = max dist; ties -> lowest index (argmax semantics)
        unsigned long long key =
            ((unsigned long long)__float_as_uint(bnd) << 32) |
            ((unsigned long long)(unsigned)(N_POINTS - bj) << 2) | tag2;

        // ---- wave butterfly carrying payload ----
#pragma unroll
        for (int m = 32; m > 0; m >>= 1) {
            unsigned long long ok = shfl_xor_u64(key, m);
            float ox = __shfl_xor(bx, m, 64);
            float oy = __shfl_xor(by, m, 64);
            float oz = __shfl_xor(bz, m, 64);
            if (ok > key) { key = ok; bx = ox; by = oy; bz = oz; }
        }
        if (lane == 0) { ldsk[wid] = key; ldsx[wid] = bx; ldsy[wid] = by; ldsz[wid] = bz; }
        __syncthreads();   // barrier 1: block records ready

        if (wid == 0) {
            // ---- block reduce: lanes 0-3 hold the 4 wave records ----
            unsigned long long K = 0ull; float X = 0.f, Y = 0.f, Z = 0.f;
            if (lane < 4) { K = ldsk[lane]; X = ldsx[lane]; Y = ldsy[lane]; Z = ldsz[lane]; }
            if (lane < 4) {
#pragma unroll
                for (int m = 1; m <= 2; m <<= 1) {
                    unsigned long long oK = shfl_xor_u64(K, m);
                    float oX = __shfl_xor(X, m, 64);
                    float oY = __shfl_xor(Y, m, 64);
                    float oZ = __shfl_xor(Z, m, 64);
                    if (oK > K) { K = oK; X = oX; Y = oY; Z = oZ; }
                }
                // ---- publish block record: lane p stores plane p (1 instr, 4 lanes) ----
                unsigned long long* row = slot + (size_t)(i & 1) * ROWU64;
                float c = (lane == 1) ? X : (lane == 2) ? Y : Z;
                unsigned long long cv =
                    ((unsigned long long)__float_as_uint(c) << 32) | tag2;
                unsigned long long myval = (lane == 0) ? K : cv;
                STORESLOT(row + lane * NBLK + bid, myval);
            }

            // ---- poll: lane l owns block-record l; 4 lane-contiguous 512B loads ----
            const unsigned long long* row = slot + (size_t)(i & 1) * ROWU64;
            unsigned long long kv, xv, yv, zv;
            for (;;) {
                kv = LOADSLOT(row + lane);
                xv = LOADSLOT(row + NBLK + lane);
                yv = LOADSLOT(row + 2 * NBLK + lane);
                zv = LOADSLOT(row + 3 * NBLK + lane);
                bool ok = ((unsigned)(kv & 3u) == tag2) & ((unsigned)(xv & 3u) == tag2)
                        & ((unsigned)(yv & 3u) == tag2) & ((unsigned)(zv & 3u) == tag2);
                if (ok) break;   // divergent loop; lanes reconverge when all exit
            }
            unsigned long long K2 = kv;
            float X2 = __uint_as_float((unsigned)(xv >> 32));
            float Y2 = __uint_as_float((unsigned)(yv >> 32));
            float Z2 = __uint_as_float((unsigned)(zv >> 32));
#pragma unroll
            for (int m = 32; m > 0; m >>= 1) {
                unsigned long long oK = shfl_xor_u64(K2, m);
                float oX = __shfl_xor(X2, m, 64);
                float oY = __shfl_xor(Y2, m, 64);
                float oZ = __shfl_xor(Z2, m, 64);
                if (oK > K2) { K2 = oK; X2 = oX; Y2 = oY; Z2 = oZ; }
            }
            if (lane == 0) {
                s_key = K2; s_x = X2; s_y = Y2; s_z = Z2;
                if (bid == 0)
                    out[i] = (int)(N_POINTS - ((unsigned)(K2 >> 2) & 0x7FFFFu));
            }
        }
        __syncthreads();   // barrier 2: winner broadcast ready
        qx = s_x; qy = s_y; qz = s_z;
        (void)s_key;
    }
}

extern "C" void kernel_launch(void* const* d_in, const int* in_sizes, int n_in,
                              void* d_out, int out_size, void* d_ws, size_t ws_size,
                              hipStream_t stream) {
    const float* feats = (const float*)d_in[0];
    int* out = (int*)d_out;
    unsigned long long* slot = (unsigned long long*)d_ws;  // 4 KB mailbox

    fps_init<<<2, 256, 0, stream>>>(slot, out);
    // 64 blocks x 256 thr: 1 block/CU -> co-residency guaranteed
    fps_main<<<NBLK, NTHR, 0, stream>>>(feats, out, slot);
}